// Round 1
// baseline (1396.038 us; speedup 1.0000x reference)
//
#include <hip/hip_runtime.h>
#include <hip/hip_cooperative_groups.h>

namespace cg = cooperative_groups;

// Problem constants
#define BB 8
#define NN 512
#define TT 64
#define SS 65      // T+1
#define DD 256
#define HH 256
#define G4 1024    // 4*H

__device__ __forceinline__ float fsigmoid(float x) {
    x = fminf(fmaxf(x, -30.f), 30.f);
    return 1.f / (1.f + __expf(-x));
}
__device__ __forceinline__ float ftanh(float x) {
    x = fminf(fmaxf(x, -15.f), 15.f);
    float e = __expf(-2.f * x);
    return (1.f - e) / (1.f + e);
}

// ---------------------------------------------------------------------------
// prep: materialize seq = concat(init_i, lstm_in) [B,65,D]; init h double-buffers
// ---------------------------------------------------------------------------
__global__ void prep_kernel(const float* __restrict__ lstm_in,
                            const float* __restrict__ init_i,
                            const float* __restrict__ init_h,
                            float* __restrict__ seq,
                            float* __restrict__ hbuf) {
    int idx = blockIdx.x * 256 + threadIdx.x;
    if (idx < BB * SS * DD) {
        int d = idx & 255;
        int r = idx >> 8;           // b*65 + s
        int s = r % SS, b = r / SS;
        seq[idx] = (s == 0) ? init_i[d]
                            : lstm_in[((size_t)b * TT + (s - 1)) * DD + d];
    } else {
        int i2 = idx - BB * SS * DD;     // [2 parity][2 layer][8 b][256 h]
        int h = i2 & 255;
        int l = (i2 >> 11) & 1;
        hbuf[i2] = init_h[l * HH + h];
    }
}

// ---------------------------------------------------------------------------
// generic 64x64-tile fp32 GEMM.  C[M,N] = A[M,K] @ (TRANSB ? B[N,K]^T : B[K,N])
//                                + bias0[n] + bias1[n]
// ---------------------------------------------------------------------------
template<bool TRANSB>
__global__ void gemm_kernel(const float* __restrict__ A, const float* __restrict__ B,
                            float* __restrict__ C, int M, int N, int K,
                            const float* __restrict__ bias0,
                            const float* __restrict__ bias1) {
    __shared__ float As[16][68];
    __shared__ float Bs[16][68];
    const int tid = threadIdx.x;
    const int bm = blockIdx.x * 64, bn = blockIdx.y * 64;
    const int tm = (tid >> 4) * 4, tn = (tid & 15) * 4;
    const int arow = tid >> 2, akq = (tid & 3) << 2;
    float acc[4][4] = {};
    for (int k0 = 0; k0 < K; k0 += 16) {
        {
            int m = bm + arow;
            float4 v = make_float4(0.f, 0.f, 0.f, 0.f);
            if (m < M) v = *(const float4*)(A + (size_t)m * K + k0 + akq);
            As[akq + 0][arow] = v.x; As[akq + 1][arow] = v.y;
            As[akq + 2][arow] = v.z; As[akq + 3][arow] = v.w;
        }
        if (TRANSB) {
            int n = bn + arow;  // N is a multiple of 64
            float4 v = *(const float4*)(B + (size_t)n * K + k0 + akq);
            Bs[akq + 0][n - bn] = v.x; Bs[akq + 1][n - bn] = v.y;
            Bs[akq + 2][n - bn] = v.z; Bs[akq + 3][n - bn] = v.w;
        } else {
            int kk = tid >> 4, nq = (tid & 15) << 2;
            float4 v = *(const float4*)(B + (size_t)(k0 + kk) * N + bn + nq);
            *(float4*)&Bs[kk][nq] = v;
        }
        __syncthreads();
#pragma unroll
        for (int kk = 0; kk < 16; ++kk) {
            float4 a = *(const float4*)&As[kk][tm];
            float4 b = *(const float4*)&Bs[kk][tn];
            float av[4] = {a.x, a.y, a.z, a.w};
            float bv[4] = {b.x, b.y, b.z, b.w};
#pragma unroll
            for (int i = 0; i < 4; ++i)
#pragma unroll
                for (int j = 0; j < 4; ++j)
                    acc[i][j] = fmaf(av[i], bv[j], acc[i][j]);
        }
        __syncthreads();
    }
    float bad[4] = {0.f, 0.f, 0.f, 0.f};
    if (bias0) {
#pragma unroll
        for (int j = 0; j < 4; ++j) bad[j] += bias0[bn + tn + j];
    }
    if (bias1) {
#pragma unroll
        for (int j = 0; j < 4; ++j) bad[j] += bias1[bn + tn + j];
    }
#pragma unroll
    for (int i = 0; i < 4; ++i) {
        int m = bm + tm + i;
        if (m < M) {
            float4 r = make_float4(acc[i][0] + bad[0], acc[i][1] + bad[1],
                                   acc[i][2] + bad[2], acc[i][3] + bad[3]);
            *(float4*)(C + (size_t)m * N + bn + tn) = r;
        }
    }
}

// ---------------------------------------------------------------------------
// persistent cooperative 2-layer LSTM, layer-skewed: window t computes
// layer0 step t (t<65) and layer1 step t-1 (t>=1).  66 grid syncs.
// blocks 0..31: layer0 (8 j each); blocks 32..95: layer1 (4 j each).
// ---------------------------------------------------------------------------
__global__ void __launch_bounds__(256) lstm_kernel(
    const float* __restrict__ w_hh,    // [2][1024][256]
    const float* __restrict__ w_ih,    // [2][1024][256]
    const float* __restrict__ b_ih,    // [2][1024]
    const float* __restrict__ b_hh,    // [2][1024]
    const float* __restrict__ xg0,     // [8][65][1024] (layer0 biases included)
    const float* __restrict__ init_c,  // [2][256]
    float* __restrict__ hbuf,          // [2 parity][2 layer][8][256]
    float* __restrict__ query)         // [8][65][256]
{
    __shared__ float h0s[8][260];
    __shared__ float h1s[8][260];
    __shared__ float part[512];
    __shared__ float cs[8][8];         // [b][j_local] persistent cell state
    cg::grid_group grid = cg::this_grid();
    const int tid = threadIdx.x;
    const int blk = blockIdx.x;
    const bool is1 = blk >= 32;

    int jl, gate, b, half, j0, pidx;
    const float* wrow;
    if (!is1) {
        j0 = blk * 8;
        jl = tid >> 5; gate = (tid >> 3) & 3; b = tid & 7; half = 0;
        wrow = w_hh + (size_t)(gate * HH + j0 + jl) * HH;
        pidx = (jl * 4 + gate) * 8 + b;
    } else {
        j0 = (blk - 32) * 4;
        jl = tid >> 6; gate = (tid >> 4) & 3; b = (tid >> 1) & 7; half = tid & 1;
        const float* base = half ? (w_hh + (size_t)G4 * HH) : (w_ih + (size_t)G4 * HH);
        wrow = base + (size_t)(gate * HH + j0 + jl) * HH;
        pidx = ((jl * 4 + gate) * 8 + b) * 2 + half;
    }
    // init cell state (writer thread == later reader thread, but sync anyway)
    if (!is1) { if (tid < 64) cs[tid & 7][tid >> 3] = init_c[j0 + (tid >> 3)]; }
    else      { if (tid < 32) cs[tid & 7][tid >> 3] = init_c[HH + j0 + (tid >> 3)]; }
    const float4* wp = (const float4*)wrow;
    __syncthreads();

    for (int t = 0; t <= SS; ++t) {
        const float* hb = hbuf + ((t + 1) & 1) * 4096;
#pragma unroll
        for (int i = 0; i < 8; ++i) h0s[i][tid] = hb[i * 256 + tid];
        if (is1) {
#pragma unroll
            for (int i = 0; i < 8; ++i) h1s[i][tid] = hb[2048 + i * 256 + tid];
        }
        __syncthreads();
        const bool active = is1 ? (t >= 1) : (t < SS);
        if (active) {
            const float4* hp = (const float4*)((is1 && half) ? &h1s[b][0] : &h0s[b][0]);
            float4 s4 = make_float4(0.f, 0.f, 0.f, 0.f);
#pragma unroll 8
            for (int k = 0; k < 64; ++k) {
                float4 w4 = wp[k];
                float4 h4 = hp[k];
                s4.x = fmaf(w4.x, h4.x, s4.x);
                s4.y = fmaf(w4.y, h4.y, s4.y);
                s4.z = fmaf(w4.z, h4.z, s4.z);
                s4.w = fmaf(w4.w, h4.w, s4.w);
            }
            part[pidx] = (s4.x + s4.y) + (s4.z + s4.w);
        }
        __syncthreads();
        if (active) {
            if (!is1 && tid < 64) {
                int jj = tid >> 3, bb = tid & 7;
                const float* xg = xg0 + ((size_t)bb * SS + t) * G4 + (j0 + jj);
                float gi = xg[0]   + part[(jj * 4 + 0) * 8 + bb];
                float gf = xg[256] + part[(jj * 4 + 1) * 8 + bb];
                float gg = xg[512] + part[(jj * 4 + 2) * 8 + bb];
                float go = xg[768] + part[(jj * 4 + 3) * 8 + bb];
                float c = fsigmoid(gf) * cs[bb][jj] + fsigmoid(gi) * ftanh(gg);
                float h = fsigmoid(go) * ftanh(c);
                cs[bb][jj] = c;
                hbuf[(t & 1) * 4096 + bb * 256 + (j0 + jj)] = h;
            } else if (is1 && tid < 32) {
                int jj = tid >> 3, bb = tid & 7;
                int j = j0 + jj;
                float gs[4];
#pragma unroll
                for (int g2 = 0; g2 < 4; ++g2)
                    gs[g2] = part[((jj * 4 + g2) * 8 + bb) * 2]
                           + part[((jj * 4 + g2) * 8 + bb) * 2 + 1]
                           + b_ih[G4 + g2 * HH + j] + b_hh[G4 + g2 * HH + j];
                float c = fsigmoid(gs[1]) * cs[bb][jj] + fsigmoid(gs[0]) * ftanh(gs[2]);
                float h = fsigmoid(gs[3]) * ftanh(c);
                cs[bb][jj] = c;
                hbuf[(t & 1) * 4096 + 2048 + bb * 256 + j] = h;
                query[((size_t)bb * SS + (t - 1)) * HH + j] = h;
            }
        }
        grid.sync();
    }
}

// ---------------------------------------------------------------------------
// additive score: out[b,s,n] = sum_h tanh(feat[b,n,h] + q[b,s,h]) * v[h]
// masked: n >= mem_sizes[b] -> -1e18 (skip the dot entirely)
// ---------------------------------------------------------------------------
__global__ void score_kernel(const float* __restrict__ feat, const float* __restrict__ q,
                             const float* __restrict__ v, const int* __restrict__ mem_sizes,
                             float* __restrict__ out, int masked) {
    const int s = blockIdx.x, b = blockIdx.y;
    __shared__ float qs[256], vs[256];
    const int tid = threadIdx.x;
    qs[tid] = q[((size_t)b * SS + s) * HH + tid];
    vs[tid] = v[tid];
    __syncthreads();
    const int lane = tid & 63, wv = tid >> 6;
    const int msize = masked ? mem_sizes[b] : NN;
    const float* fb = feat + (size_t)b * NN * HH;
    float* ob = out + ((size_t)b * SS + s) * NN;
    float4 q4 = *(const float4*)&qs[lane << 2];
    float4 v4 = *(const float4*)&vs[lane << 2];
    for (int n = wv; n < NN; n += 4) {
        if (n >= msize) { if (lane == 0) ob[n] = -1e18f; continue; }
        float4 f4 = *(const float4*)(fb + (size_t)n * HH + (lane << 2));
        float acc = ftanh(f4.x + q4.x) * v4.x;
        acc += ftanh(f4.y + q4.y) * v4.y;
        acc += ftanh(f4.z + q4.z) * v4.z;
        acc += ftanh(f4.w + q4.w) * v4.w;
#pragma unroll
        for (int off = 32; off; off >>= 1) acc += __shfl_xor(acc, off, 64);
        if (lane == 0) ob[n] = acc;
    }
}

// ---------------------------------------------------------------------------
// row softmax over n (512), in place
// ---------------------------------------------------------------------------
__global__ void softmax_kernel(float* __restrict__ score) {
    const int s = blockIdx.x, b = blockIdx.y;
    float* row = score + ((size_t)b * SS + s) * NN;
    const int tid = threadIdx.x;
    __shared__ float red[8];
    float v0 = row[tid], v1 = row[tid + 256];
    float m = fmaxf(v0, v1);
#pragma unroll
    for (int off = 32; off; off >>= 1) m = fmaxf(m, __shfl_xor(m, off, 64));
    if ((tid & 63) == 0) red[tid >> 6] = m;
    __syncthreads();
    m = fmaxf(fmaxf(red[0], red[1]), fmaxf(red[2], red[3]));
    float e0 = __expf(v0 - m), e1 = __expf(v1 - m);
    float sum = e0 + e1;
#pragma unroll
    for (int off = 32; off; off >>= 1) sum += __shfl_xor(sum, off, 64);
    if ((tid & 63) == 0) red[4 + (tid >> 6)] = sum;
    __syncthreads();
    float inv = 1.f / (red[4] + red[5] + red[6] + red[7]);
    row[tid] = e0 * inv;
    row[tid + 256] = e1 * inv;
}

// ---------------------------------------------------------------------------
// query2[b,s,h] = sum_n norm[b,s,n] * feat[b,n,h]   (5 s per block)
// ---------------------------------------------------------------------------
__global__ void wsum_kernel(const float* __restrict__ norm, const float* __restrict__ feat,
                            float* __restrict__ out) {
    const int b = blockIdx.y, s0 = blockIdx.x * 5;
    const int tid = threadIdx.x;
    __shared__ float ns[5][512];
    for (int i = tid; i < 5 * 512; i += 256) {
        int ss2 = i >> 9, nn2 = i & 511;
        ns[ss2][nn2] = norm[((size_t)b * SS + s0 + ss2) * NN + nn2];
    }
    __syncthreads();
    float acc[5] = {0.f, 0.f, 0.f, 0.f, 0.f};
    const float* fb = feat + (size_t)b * NN * HH + tid;
    for (int n = 0; n < NN; ++n) {
        float f = fb[(size_t)n * HH];
#pragma unroll
        for (int i = 0; i < 5; ++i) acc[i] = fmaf(ns[i][n], f, acc[i]);
    }
#pragma unroll
    for (int i = 0; i < 5; ++i)
        out[((size_t)b * SS + s0 + i) * HH + tid] = acc[i];
}

// ---------------------------------------------------------------------------
extern "C" void kernel_launch(void* const* d_in, const int* in_sizes, int n_in,
                              void* d_out, int out_size, void* d_ws, size_t ws_size,
                              hipStream_t stream) {
    const float* attn_mem  = (const float*)d_in[0];
    const int*   mem_sizes = (const int*)d_in[1];
    const float* lstm_in   = (const float*)d_in[2];
    const float* init_h    = (const float*)d_in[3];
    const float* init_c    = (const float*)d_in[4];
    const float* init_i    = (const float*)d_in[5];
    const float* w_ih      = (const float*)d_in[6];
    const float* w_hh      = (const float*)d_in[7];
    const float* b_ih      = (const float*)d_in[8];
    const float* b_hh      = (const float*)d_in[9];
    const float* attn_wm   = (const float*)d_in[10];
    const float* attn_wq   = (const float*)d_in[11];
    const float* attn_v    = (const float*)d_in[12];
    const float* hop_wm    = (const float*)d_in[13];
    const float* hop_wq    = (const float*)d_in[14];
    const float* hop_v     = (const float*)d_in[15];
    float* out = (float*)d_out;

    float* ws        = (float*)d_ws;
    float* attn_feat = ws;                 // 1048576
    float* hop_feat  = ws + 1048576;       // 1048576
    float* seq       = ws + 2097152;       // 133120
    float* xg0       = ws + 2230272;       // 532480
    float* query     = ws + 2762752;       // 133120
    float* q1        = ws + 2895872;       // 133120
    float* score     = ws + 3028992;       // 266240
    float* query2    = ws + 3295232;       // 133120
    float* q2        = ws + 3428352;       // 133120
    float* hbuf      = ws + 3561472;       // 8192

    prep_kernel<<<552, 256, 0, stream>>>(lstm_in, init_i, init_h, seq, hbuf);
    gemm_kernel<false><<<dim3(64, 4), 256, 0, stream>>>(attn_mem, attn_wm, attn_feat,
                                                        4096, 256, 256, nullptr, nullptr);
    gemm_kernel<false><<<dim3(64, 4), 256, 0, stream>>>(attn_mem, hop_wm, hop_feat,
                                                        4096, 256, 256, nullptr, nullptr);
    gemm_kernel<true><<<dim3(9, 16), 256, 0, stream>>>(seq, w_ih, xg0,
                                                       520, 1024, 256, b_ih, b_hh);
    {
        void* args[] = { (void*)&w_hh, (void*)&w_ih, (void*)&b_ih, (void*)&b_hh,
                         (void*)&xg0, (void*)&init_c, (void*)&hbuf, (void*)&query };
        hipLaunchCooperativeKernel(lstm_kernel, dim3(96), dim3(256), args, 0u, stream);
    }
    gemm_kernel<false><<<dim3(9, 4), 256, 0, stream>>>(query, hop_wq, q1,
                                                       520, 256, 256, nullptr, nullptr);
    score_kernel<<<dim3(65, 8), 256, 0, stream>>>(hop_feat, q1, hop_v, mem_sizes, score, 1);
    softmax_kernel<<<dim3(65, 8), 256, 0, stream>>>(score);
    wsum_kernel<<<dim3(13, 8), 256, 0, stream>>>(score, hop_feat, query2);
    gemm_kernel<false><<<dim3(9, 4), 256, 0, stream>>>(query2, attn_wq, q2,
                                                       520, 256, 256, nullptr, nullptr);
    score_kernel<<<dim3(65, 8), 256, 0, stream>>>(attn_feat, q2, attn_v, mem_sizes, out, 0);
}

// Round 2
// 515.040 us; speedup vs baseline: 2.7105x; 2.7105x over previous
//
#include <hip/hip_runtime.h>

// Problem constants
#define BB 8
#define NN 512
#define TT 64
#define SS 65      // T+1
#define DD 256
#define HH 256
#define G4 1024    // 4*H

__device__ __forceinline__ float fsigmoid(float x) {
    x = fminf(fmaxf(x, -30.f), 30.f);
    return 1.f / (1.f + __expf(-x));
}
__device__ __forceinline__ float ftanh(float x) {
    x = fminf(fmaxf(x, -15.f), 15.f);
    float e = __expf(-2.f * x);
    return (1.f - e) / (1.f + e);
}

// ---------------------------------------------------------------------------
// prep: seq = concat(init_i, lstm_in) [B,65,D]; hseq slot0 = init_h; flags.
// flags[0..65] = flag0 (h0 step slots), flags[66..131] = flag1.
// ---------------------------------------------------------------------------
__global__ void prep_kernel(const float* __restrict__ lstm_in,
                            const float* __restrict__ init_i,
                            const float* __restrict__ init_h,
                            float* __restrict__ seq,
                            float* __restrict__ hseq0,
                            float* __restrict__ hseq1,
                            int* __restrict__ flags) {
    int idx = blockIdx.x * 256 + threadIdx.x;
    if (idx < BB * SS * DD) {
        int d = idx & 255;
        int r = idx >> 8;           // b*65 + s
        int s = r % SS, b = r / SS;
        seq[idx] = (s == 0) ? init_i[d]
                            : lstm_in[((size_t)b * TT + (s - 1)) * DD + d];
    } else if (idx < BB * SS * DD + 2048) {
        int i2 = idx - BB * SS * DD;
        hseq0[i2] = init_h[i2 & 255];
    } else if (idx < BB * SS * DD + 4096) {
        int i2 = idx - BB * SS * DD - 2048;
        hseq1[i2] = init_h[HH + (i2 & 255)];
    } else if (idx < BB * SS * DD + 4096 + 132) {
        int f = idx - (BB * SS * DD + 4096);
        flags[f] = (f == 0) ? 32 : ((f == 66) ? 64 : 0);
    }
}

// ---------------------------------------------------------------------------
// generic 64x64-tile fp32 GEMM.  C[M,N] = A[M,K] @ (TRANSB ? B[N,K]^T : B[K,N])
//                                + bias0[n] + bias1[n]
// ---------------------------------------------------------------------------
template<bool TRANSB>
__global__ void gemm_kernel(const float* __restrict__ A, const float* __restrict__ B,
                            float* __restrict__ C, int M, int N, int K,
                            const float* __restrict__ bias0,
                            const float* __restrict__ bias1) {
    __shared__ float As[16][68];
    __shared__ float Bs[16][68];
    const int tid = threadIdx.x;
    const int bm = blockIdx.x * 64, bn = blockIdx.y * 64;
    const int tm = (tid >> 4) * 4, tn = (tid & 15) * 4;
    const int arow = tid >> 2, akq = (tid & 3) << 2;
    float acc[4][4] = {};
    for (int k0 = 0; k0 < K; k0 += 16) {
        {
            int m = bm + arow;
            float4 v = make_float4(0.f, 0.f, 0.f, 0.f);
            if (m < M) v = *(const float4*)(A + (size_t)m * K + k0 + akq);
            As[akq + 0][arow] = v.x; As[akq + 1][arow] = v.y;
            As[akq + 2][arow] = v.z; As[akq + 3][arow] = v.w;
        }
        if (TRANSB) {
            int n = bn + arow;  // N is a multiple of 64
            float4 v = *(const float4*)(B + (size_t)n * K + k0 + akq);
            Bs[akq + 0][n - bn] = v.x; Bs[akq + 1][n - bn] = v.y;
            Bs[akq + 2][n - bn] = v.z; Bs[akq + 3][n - bn] = v.w;
        } else {
            int kk = tid >> 4, nq = (tid & 15) << 2;
            float4 v = *(const float4*)(B + (size_t)(k0 + kk) * N + bn + nq);
            *(float4*)&Bs[kk][nq] = v;
        }
        __syncthreads();
#pragma unroll
        for (int kk = 0; kk < 16; ++kk) {
            float4 a = *(const float4*)&As[kk][tm];
            float4 b = *(const float4*)&Bs[kk][tn];
            float av[4] = {a.x, a.y, a.z, a.w};
            float bv[4] = {b.x, b.y, b.z, b.w};
#pragma unroll
            for (int i = 0; i < 4; ++i)
#pragma unroll
                for (int j = 0; j < 4; ++j)
                    acc[i][j] = fmaf(av[i], bv[j], acc[i][j]);
        }
        __syncthreads();
    }
    float bad[4] = {0.f, 0.f, 0.f, 0.f};
    if (bias0) {
#pragma unroll
        for (int j = 0; j < 4; ++j) bad[j] += bias0[bn + tn + j];
    }
    if (bias1) {
#pragma unroll
        for (int j = 0; j < 4; ++j) bad[j] += bias1[bn + tn + j];
    }
#pragma unroll
    for (int i = 0; i < 4; ++i) {
        int m = bm + tm + i;
        if (m < M) {
            float4 r = make_float4(acc[i][0] + bad[0], acc[i][1] + bad[1],
                                   acc[i][2] + bad[2], acc[i][3] + bad[3]);
            *(float4*)(C + (size_t)m * N + bn + tn) = r;
        }
    }
}

// ---------------------------------------------------------------------------
// persistent 2-layer LSTM, dataflow-synced (no grid.sync).
// 96 blocks x 1024 threads. Blocks 0..31: layer0 (8 j-rows each).
// Blocks 32..95: layer1 (4 j-rows each).
// Weights live in registers (64 floats/thread). Cross-block h exchange via
// agent-scope (coherent-point) loads/stores + per-step flag atomics.
// ---------------------------------------------------------------------------
__device__ __forceinline__ float dot16(const float4* w, const float* hp) {
    float4 s = make_float4(0.f, 0.f, 0.f, 0.f);
#pragma unroll
    for (int k = 0; k < 16; ++k) {
        float4 h4 = *(const float4*)(hp + 4 * k);
        s.x = fmaf(w[k].x, h4.x, s.x);
        s.y = fmaf(w[k].y, h4.y, s.y);
        s.z = fmaf(w[k].z, h4.z, s.z);
        s.w = fmaf(w[k].w, h4.w, s.w);
    }
    return (s.x + s.y) + (s.z + s.w);
}

__device__ __forceinline__ void spin_ge(const int* f, int target) {
    while (__hip_atomic_load(f, __ATOMIC_RELAXED, __HIP_MEMORY_SCOPE_AGENT) < target)
        __builtin_amdgcn_s_sleep(1);
}

__global__ void __launch_bounds__(1024) lstm_kernel(
    const float* __restrict__ w_ih, const float* __restrict__ w_hh,
    const float* __restrict__ b_ih, const float* __restrict__ b_hh,
    const float* __restrict__ xg0, const float* __restrict__ init_c,
    float* __restrict__ hseq0, float* __restrict__ hseq1,
    int* __restrict__ flags, float* __restrict__ query)
{
    __shared__ float hls[64 * 68];
    __shared__ float part[1024];
    const int tid = threadIdx.x;
    const int blk = blockIdx.x;
    int* flag0 = flags;
    int* flag1 = flags + 66;

    if (blk < 32) {
        // ------------------------ layer 0 ------------------------
        const int jl   = tid & 7;
        const int gate = (tid >> 3) & 3;
        const int b    = (tid >> 5) & 7;
        const int seg  = tid >> 8;           // 0..3
        const int j0   = blk * 8;
        const int j    = j0 + jl;
        float4 w[16];
        {
            const float4* wr = (const float4*)(w_hh + (size_t)(gate * HH + j) * HH + seg * 64);
#pragma unroll
            for (int k = 0; k < 16; ++k) w[k] = wr[k];
        }
        const int fj = tid >> 3, fb = tid & 7;   // finisher mapping (tid<64)
        float creg = (tid < 64) ? init_c[j0 + fj] : 0.f;
        const int chunk = seg * 8 + b;

        for (int t = 0; t < SS; ++t) {
            // prefetch xg for this step (issues before spin; retires during it)
            float xg[4];
            if (tid < 64) {
                const float* xp = xg0 + ((size_t)fb * SS + t) * G4 + (j0 + fj);
#pragma unroll
                for (int g = 0; g < 4; ++g) xg[g] = xp[g * 256];
            }
            if (tid == 0) spin_ge(flag0 + t, 32);
            __builtin_amdgcn_fence(__ATOMIC_ACQUIRE, "workgroup");
            __syncthreads();
            {   // stage h0[t] -> LDS chunks (coherent-point load)
                unsigned long long u = __hip_atomic_load(
                    (const unsigned long long*)(hseq0 + (size_t)t * 2048) + tid,
                    __ATOMIC_RELAXED, __HIP_MEMORY_SCOPE_AGENT);
                union { unsigned long long u; float f[2]; } cv; cv.u = u;
                int g = tid * 2, sb = g >> 8, r = g & 255, sg = r >> 6, k = r & 63;
                float* dst = &hls[(sg * 8 + sb) * 68 + k];
                dst[0] = cv.f[0]; dst[1] = cv.f[1];
            }
            __syncthreads();
            part[(chunk * 8 + jl) * 4 + gate] = dot16(w, &hls[chunk * 68]);
            __syncthreads();
            if (tid < 64) {
                float g0 = xg[0], g1 = xg[1], g2 = xg[2], g3 = xg[3];
#pragma unroll
                for (int s2 = 0; s2 < 4; ++s2) {
                    const float* pp = &part[((s2 * 8 + fb) * 8 + fj) * 4];
                    g0 += pp[0]; g1 += pp[1]; g2 += pp[2]; g3 += pp[3];
                }
                float c = fsigmoid(g1) * creg + fsigmoid(g0) * ftanh(g2);
                float h = fsigmoid(g3) * ftanh(c);
                creg = c;
                __hip_atomic_store(hseq0 + (size_t)(t + 1) * 2048 + fb * 256 + (j0 + fj), h,
                                   __ATOMIC_RELAXED, __HIP_MEMORY_SCOPE_AGENT);
                asm volatile("s_waitcnt vmcnt(0)" ::: "memory");
            }
            __syncthreads();
            if (tid == 0)
                __hip_atomic_fetch_add(flag0 + t + 1, 1, __ATOMIC_RELAXED,
                                       __HIP_MEMORY_SCOPE_AGENT);
        }
    } else {
        // ------------------------ layer 1 ------------------------
        const int jl   = tid & 3;
        const int gate = (tid >> 2) & 3;
        const int b    = (tid >> 4) & 7;
        const int seg  = tid >> 7;           // 0..7 (0-3: w_ih on h0new, 4-7: w_hh on h1)
        const int j0   = (blk - 32) * 4;
        const int j    = j0 + jl;
        float4 w[16];
        {
            const float* base = (seg < 4)
                ? (w_ih + (size_t)(G4 + gate * HH + j) * HH + seg * 64)
                : (w_hh + (size_t)(G4 + gate * HH + j) * HH + (seg - 4) * 64);
            const float4* wr = (const float4*)base;
#pragma unroll
            for (int k = 0; k < 16; ++k) w[k] = wr[k];
        }
        float creg = 0.f, bias[4] = {0.f, 0.f, 0.f, 0.f};
        if (tid < 32) {
            int fj = tid >> 3;
            creg = init_c[HH + j0 + fj];
#pragma unroll
            for (int g = 0; g < 4; ++g)
                bias[g] = b_ih[G4 + g * HH + j0 + fj] + b_hh[G4 + g * HH + j0 + fj];
        }
        const int chunk = seg * 8 + b;

        for (int t = 0; t < SS; ++t) {
            if (tid == 0) spin_ge(flag0 + t + 1, 32);
            __builtin_amdgcn_fence(__ATOMIC_ACQUIRE, "workgroup");
            __syncthreads();
            {   // stage h0new -> chunks 0..31
                unsigned long long u = __hip_atomic_load(
                    (const unsigned long long*)(hseq0 + (size_t)(t + 1) * 2048) + tid,
                    __ATOMIC_RELAXED, __HIP_MEMORY_SCOPE_AGENT);
                union { unsigned long long u; float f[2]; } cv; cv.u = u;
                int g = tid * 2, sb = g >> 8, r = g & 255, sg = r >> 6, k = r & 63;
                float* dst = &hls[(sg * 8 + sb) * 68 + k];
                dst[0] = cv.f[0]; dst[1] = cv.f[1];
            }
            __syncthreads();
            float acc = 0.f;
            if (seg < 4) acc = dot16(w, &hls[chunk * 68]);  // off critical path
            if (tid == 0) spin_ge(flag1 + t, 64);
            __builtin_amdgcn_fence(__ATOMIC_ACQUIRE, "workgroup");
            __syncthreads();
            {   // stage h1[t] -> chunks 32..63
                unsigned long long u = __hip_atomic_load(
                    (const unsigned long long*)(hseq1 + (size_t)t * 2048) + tid,
                    __ATOMIC_RELAXED, __HIP_MEMORY_SCOPE_AGENT);
                union { unsigned long long u; float f[2]; } cv; cv.u = u;
                int g = tid * 2, sb = g >> 8, r = g & 255, sg = r >> 6, k = r & 63;
                float* dst = &hls[(32 + sg * 8 + sb) * 68 + k];
                dst[0] = cv.f[0]; dst[1] = cv.f[1];
            }
            __syncthreads();
            if (seg >= 4) acc = dot16(w, &hls[chunk * 68]); // chunk = seg*8+b = 32+...
            part[chunk * 16 + jl * 4 + gate] = acc;
            __syncthreads();
            if (tid < 32) {
                int fj = tid >> 3, fb = tid & 7;
                float g0 = bias[0], g1 = bias[1], g2 = bias[2], g3 = bias[3];
#pragma unroll
                for (int s2 = 0; s2 < 8; ++s2) {
                    const float* pp = &part[(s2 * 8 + fb) * 16 + fj * 4];
                    g0 += pp[0]; g1 += pp[1]; g2 += pp[2]; g3 += pp[3];
                }
                float c = fsigmoid(g1) * creg + fsigmoid(g0) * ftanh(g2);
                float h = fsigmoid(g3) * ftanh(c);
                creg = c;
                int jj = j0 + fj;
                __hip_atomic_store(hseq1 + (size_t)(t + 1) * 2048 + fb * 256 + jj, h,
                                   __ATOMIC_RELAXED, __HIP_MEMORY_SCOPE_AGENT);
                query[((size_t)fb * SS + t) * HH + jj] = h;   // normal store, read post-kernel
                asm volatile("s_waitcnt vmcnt(0)" ::: "memory");
            }
            __syncthreads();
            if (tid == 0)
                __hip_atomic_fetch_add(flag1 + t + 1, 1, __ATOMIC_RELAXED,
                                       __HIP_MEMORY_SCOPE_AGENT);
        }
    }
}

// ---------------------------------------------------------------------------
// additive score: out[b,s,n] = sum_h tanh(feat[b,n,h] + q[b,s,h]) * v[h]
// ---------------------------------------------------------------------------
__global__ void score_kernel(const float* __restrict__ feat, const float* __restrict__ q,
                             const float* __restrict__ v, const int* __restrict__ mem_sizes,
                             float* __restrict__ out, int masked) {
    const int s = blockIdx.x, b = blockIdx.y;
    __shared__ float qs[256], vs[256];
    const int tid = threadIdx.x;
    qs[tid] = q[((size_t)b * SS + s) * HH + tid];
    vs[tid] = v[tid];
    __syncthreads();
    const int lane = tid & 63, wv = tid >> 6;
    const int msize = masked ? mem_sizes[b] : NN;
    const float* fb = feat + (size_t)b * NN * HH;
    float* ob = out + ((size_t)b * SS + s) * NN;
    float4 q4 = *(const float4*)&qs[lane << 2];
    float4 v4 = *(const float4*)&vs[lane << 2];
    for (int n = wv; n < NN; n += 4) {
        if (n >= msize) { if (lane == 0) ob[n] = -1e18f; continue; }
        float4 f4 = *(const float4*)(fb + (size_t)n * HH + (lane << 2));
        float acc = ftanh(f4.x + q4.x) * v4.x;
        acc += ftanh(f4.y + q4.y) * v4.y;
        acc += ftanh(f4.z + q4.z) * v4.z;
        acc += ftanh(f4.w + q4.w) * v4.w;
#pragma unroll
        for (int off = 32; off; off >>= 1) acc += __shfl_xor(acc, off, 64);
        if (lane == 0) ob[n] = acc;
    }
}

// ---------------------------------------------------------------------------
__global__ void softmax_kernel(float* __restrict__ score) {
    const int s = blockIdx.x, b = blockIdx.y;
    float* row = score + ((size_t)b * SS + s) * NN;
    const int tid = threadIdx.x;
    __shared__ float red[8];
    float v0 = row[tid], v1 = row[tid + 256];
    float m = fmaxf(v0, v1);
#pragma unroll
    for (int off = 32; off; off >>= 1) m = fmaxf(m, __shfl_xor(m, off, 64));
    if ((tid & 63) == 0) red[tid >> 6] = m;
    __syncthreads();
    m = fmaxf(fmaxf(red[0], red[1]), fmaxf(red[2], red[3]));
    float e0 = __expf(v0 - m), e1 = __expf(v1 - m);
    float sum = e0 + e1;
#pragma unroll
    for (int off = 32; off; off >>= 1) sum += __shfl_xor(sum, off, 64);
    if ((tid & 63) == 0) red[4 + (tid >> 6)] = sum;
    __syncthreads();
    float inv = 1.f / (red[4] + red[5] + red[6] + red[7]);
    row[tid] = e0 * inv;
    row[tid + 256] = e1 * inv;
}

// ---------------------------------------------------------------------------
__global__ void wsum_kernel(const float* __restrict__ norm, const float* __restrict__ feat,
                            float* __restrict__ out) {
    const int b = blockIdx.y, s0 = blockIdx.x * 5;
    const int tid = threadIdx.x;
    __shared__ float ns[5][512];
    for (int i = tid; i < 5 * 512; i += 256) {
        int ss2 = i >> 9, nn2 = i & 511;
        ns[ss2][nn2] = norm[((size_t)b * SS + s0 + ss2) * NN + nn2];
    }
    __syncthreads();
    float acc[5] = {0.f, 0.f, 0.f, 0.f, 0.f};
    const float* fb = feat + (size_t)b * NN * HH + tid;
    for (int n = 0; n < NN; ++n) {
        float f = fb[(size_t)n * HH];
#pragma unroll
        for (int i = 0; i < 5; ++i) acc[i] = fmaf(ns[i][n], f, acc[i]);
    }
#pragma unroll
    for (int i = 0; i < 5; ++i)
        out[((size_t)b * SS + s0 + i) * HH + tid] = acc[i];
}

// ---------------------------------------------------------------------------
extern "C" void kernel_launch(void* const* d_in, const int* in_sizes, int n_in,
                              void* d_out, int out_size, void* d_ws, size_t ws_size,
                              hipStream_t stream) {
    const float* attn_mem  = (const float*)d_in[0];
    const int*   mem_sizes = (const int*)d_in[1];
    const float* lstm_in   = (const float*)d_in[2];
    const float* init_h    = (const float*)d_in[3];
    const float* init_c    = (const float*)d_in[4];
    const float* init_i    = (const float*)d_in[5];
    const float* w_ih      = (const float*)d_in[6];
    const float* w_hh      = (const float*)d_in[7];
    const float* b_ih      = (const float*)d_in[8];
    const float* b_hh      = (const float*)d_in[9];
    const float* attn_wm   = (const float*)d_in[10];
    const float* attn_wq   = (const float*)d_in[11];
    const float* attn_v    = (const float*)d_in[12];
    const float* hop_wm    = (const float*)d_in[13];
    const float* hop_wq    = (const float*)d_in[14];
    const float* hop_v     = (const float*)d_in[15];
    float* out = (float*)d_out;

    float* ws        = (float*)d_ws;
    float* attn_feat = ws;                 // 1048576
    float* hop_feat  = ws + 1048576;       // 1048576
    float* seq       = ws + 2097152;       // 133120
    float* xg0       = ws + 2230272;       // 532480
    float* query     = ws + 2762752;       // 133120
    // lstm-phase region (dead after lstm_kernel), overlaid by q1/score/...
    float* hseq0     = ws + 2895872;       // 66*2048 = 135168
    float* hseq1     = ws + 3031040;       // 135168
    int*   flags     = (int*)(ws + 3166208); // 132 ints
    // post-lstm region (same bytes, different lifetime)
    float* q1        = ws + 2895872;       // 133120
    float* score     = ws + 3028992;       // 266240
    float* query2    = ws + 3295232;       // 133120
    float* q2        = ws + 3428352;       // 133120

    prep_kernel<<<537, 256, 0, stream>>>(lstm_in, init_i, init_h, seq, hseq0, hseq1, flags);
    gemm_kernel<false><<<dim3(64, 4), 256, 0, stream>>>(attn_mem, attn_wm, attn_feat,
                                                        4096, 256, 256, nullptr, nullptr);
    gemm_kernel<false><<<dim3(64, 4), 256, 0, stream>>>(attn_mem, hop_wm, hop_feat,
                                                        4096, 256, 256, nullptr, nullptr);
    gemm_kernel<true><<<dim3(9, 16), 256, 0, stream>>>(seq, w_ih, xg0,
                                                       520, 1024, 256, b_ih, b_hh);
    {
        void* args[] = { (void*)&w_ih, (void*)&w_hh, (void*)&b_ih, (void*)&b_hh,
                         (void*)&xg0, (void*)&init_c, (void*)&hseq0, (void*)&hseq1,
                         (void*)&flags, (void*)&query };
        hipLaunchCooperativeKernel(lstm_kernel, dim3(96), dim3(1024), args, 0u, stream);
    }
    gemm_kernel<false><<<dim3(9, 4), 256, 0, stream>>>(query, hop_wq, q1,
                                                       520, 256, 256, nullptr, nullptr);
    score_kernel<<<dim3(65, 8), 256, 0, stream>>>(hop_feat, q1, hop_v, mem_sizes, score, 1);
    softmax_kernel<<<dim3(65, 8), 256, 0, stream>>>(score);
    wsum_kernel<<<dim3(13, 8), 256, 0, stream>>>(score, hop_feat, query2);
    gemm_kernel<false><<<dim3(9, 4), 256, 0, stream>>>(query2, attn_wq, q2,
                                                       520, 256, 256, nullptr, nullptr);
    score_kernel<<<dim3(65, 8), 256, 0, stream>>>(attn_feat, q2, attn_v, mem_sizes, out, 0);
}

// Round 3
// 346.197 us; speedup vs baseline: 4.0325x; 1.4877x over previous
//
#include <hip/hip_runtime.h>

// Problem constants
#define BB 8
#define NN 512
#define TT 64
#define SS 65      // T+1
#define DD 256
#define HH 256
#define G4 1024    // 4*H

// fast transcendentals (v_rcp_f32 based, ~1e-5 rel err; saturate correctly at +-inf)
__device__ __forceinline__ float fsigmoid(float x) {
    return __builtin_amdgcn_rcpf(1.f + __expf(-x));
}
__device__ __forceinline__ float ftanh(float x) {
    float e = __expf(2.f * x);
    return fmaf(-2.f, __builtin_amdgcn_rcpf(e + 1.f), 1.f);
}

// ---------------------------------------------------------------------------
// prep: seq = concat(init_i, lstm_in) [B,65,D]; seed S0/S1 slot 0 (tag=1),
// zero tags of slots 1..65.  S layout: [66 slots][8 b][256 j] of (h,tag) u64.
// Re-inits every launch -> no stale-tag leakage across graph replays.
// ---------------------------------------------------------------------------
__global__ void prep_kernel(const float* __restrict__ lstm_in,
                            const float* __restrict__ init_i,
                            const float* __restrict__ init_h,
                            float* __restrict__ seq,
                            unsigned long long* __restrict__ S0,
                            unsigned long long* __restrict__ S1) {
    int idx = blockIdx.x * 256 + threadIdx.x;
    if (idx < BB * SS * DD) {
        int d = idx & 255;
        int r = idx >> 8;           // b*65 + s
        int s = r % SS, b = r / SS;
        seq[idx] = (s == 0) ? init_i[d]
                            : lstm_in[((size_t)b * TT + (s - 1)) * DD + d];
    } else {
        int i = idx - BB * SS * DD;
        if (i < 2048) {
            S0[i] = (1ULL << 32) | (unsigned)__float_as_uint(init_h[i & 255]);
        } else if (i < 4096) {
            S1[i - 2048] = (1ULL << 32) | (unsigned)__float_as_uint(init_h[HH + (i & 255)]);
        } else if (i < 4096 + 65 * 2048) {
            S0[2048 + (i - 4096)] = 0ULL;
        } else {
            S1[2048 + (i - (4096 + 65 * 2048))] = 0ULL;
        }
    }
}

// ---------------------------------------------------------------------------
// merged big-GEMM kernel.
// blocks [0,256):  feat pair  C1=attn_mem@attn_wm, C2=attn_mem@hop_wm (4096x256x256)
// blocks [256,400): xg0 = seq @ w_ih[0]^T + b_ih[0] + b_hh[0]  (520x1024x256)
// ---------------------------------------------------------------------------
__global__ void __launch_bounds__(256) mega_gemm_kernel(
    const float* __restrict__ attn_mem, const float* __restrict__ attn_wm,
    const float* __restrict__ hop_wm, float* __restrict__ attn_feat,
    float* __restrict__ hop_feat, const float* __restrict__ seq,
    const float* __restrict__ w_ih, const float* __restrict__ b_ih,
    const float* __restrict__ b_hh, float* __restrict__ xg0)
{
    __shared__ float As[16][68];
    __shared__ float Bs[16][68];
    __shared__ float Bs2[16][68];
    const int tid = threadIdx.x;
    const int tm = (tid >> 4) * 4, tn = (tid & 15) * 4;
    const int arow = tid >> 2, akq = (tid & 3) << 2;

    if (blockIdx.x < 256) {
        const int bm = (blockIdx.x & 63) * 64, bn = (blockIdx.x >> 6) * 64;
        float acc1[4][4] = {}, acc2[4][4] = {};
        for (int k0 = 0; k0 < 256; k0 += 16) {
            float4 va = *(const float4*)(attn_mem + (size_t)(bm + arow) * 256 + k0 + akq);
            As[akq + 0][arow] = va.x; As[akq + 1][arow] = va.y;
            As[akq + 2][arow] = va.z; As[akq + 3][arow] = va.w;
            int kk = tid >> 4, nq = (tid & 15) << 2;
            *(float4*)&Bs[kk][nq]  = *(const float4*)(attn_wm + (size_t)(k0 + kk) * 256 + bn + nq);
            *(float4*)&Bs2[kk][nq] = *(const float4*)(hop_wm  + (size_t)(k0 + kk) * 256 + bn + nq);
            __syncthreads();
#pragma unroll
            for (int kk2 = 0; kk2 < 16; ++kk2) {
                float4 a  = *(const float4*)&As[kk2][tm];
                float4 b1 = *(const float4*)&Bs[kk2][tn];
                float4 b2 = *(const float4*)&Bs2[kk2][tn];
                float av[4] = {a.x, a.y, a.z, a.w};
                float b1v[4] = {b1.x, b1.y, b1.z, b1.w};
                float b2v[4] = {b2.x, b2.y, b2.z, b2.w};
#pragma unroll
                for (int i = 0; i < 4; ++i)
#pragma unroll
                    for (int jj = 0; jj < 4; ++jj) {
                        acc1[i][jj] = fmaf(av[i], b1v[jj], acc1[i][jj]);
                        acc2[i][jj] = fmaf(av[i], b2v[jj], acc2[i][jj]);
                    }
            }
            __syncthreads();
        }
#pragma unroll
        for (int i = 0; i < 4; ++i) {
            int m = bm + tm + i;
            *(float4*)(attn_feat + (size_t)m * 256 + bn + tn) =
                make_float4(acc1[i][0], acc1[i][1], acc1[i][2], acc1[i][3]);
            *(float4*)(hop_feat + (size_t)m * 256 + bn + tn) =
                make_float4(acc2[i][0], acc2[i][1], acc2[i][2], acc2[i][3]);
        }
    } else {
        const int blk2 = blockIdx.x - 256;
        const int bm = (blk2 % 9) * 64, bn = (blk2 / 9) * 64;  // M=520, N=1024
        float acc[4][4] = {};
        for (int k0 = 0; k0 < 256; k0 += 16) {
            {
                int m = bm + arow;
                float4 v = make_float4(0.f, 0.f, 0.f, 0.f);
                if (m < 520) v = *(const float4*)(seq + (size_t)m * 256 + k0 + akq);
                As[akq + 0][arow] = v.x; As[akq + 1][arow] = v.y;
                As[akq + 2][arow] = v.z; As[akq + 3][arow] = v.w;
            }
            {   // TRANSB: B[N,K]
                int n = bn + arow;
                float4 v = *(const float4*)(w_ih + (size_t)n * 256 + k0 + akq);
                Bs[akq + 0][n - bn] = v.x; Bs[akq + 1][n - bn] = v.y;
                Bs[akq + 2][n - bn] = v.z; Bs[akq + 3][n - bn] = v.w;
            }
            __syncthreads();
#pragma unroll
            for (int kk2 = 0; kk2 < 16; ++kk2) {
                float4 a = *(const float4*)&As[kk2][tm];
                float4 b = *(const float4*)&Bs[kk2][tn];
                float av[4] = {a.x, a.y, a.z, a.w};
                float bv[4] = {b.x, b.y, b.z, b.w};
#pragma unroll
                for (int i = 0; i < 4; ++i)
#pragma unroll
                    for (int jj = 0; jj < 4; ++jj)
                        acc[i][jj] = fmaf(av[i], bv[jj], acc[i][jj]);
            }
            __syncthreads();
        }
        float bad[4];
#pragma unroll
        for (int jj = 0; jj < 4; ++jj)
            bad[jj] = b_ih[bn + tn + jj] + b_hh[bn + tn + jj];
#pragma unroll
        for (int i = 0; i < 4; ++i) {
            int m = bm + tm + i;
            if (m < 520)
                *(float4*)(xg0 + (size_t)m * 1024 + bn + tn) =
                    make_float4(acc[i][0] + bad[0], acc[i][1] + bad[1],
                                acc[i][2] + bad[2], acc[i][3] + bad[3]);
        }
    }
}

// ---------------------------------------------------------------------------
// small fp32 GEMM (64x64 tile), C = A[M,K] @ B[K,N]   (for q1/q2)
// ---------------------------------------------------------------------------
__global__ void gemm_kernel(const float* __restrict__ A, const float* __restrict__ B,
                            float* __restrict__ C, int M, int N, int K) {
    __shared__ float As[16][68];
    __shared__ float Bs[16][68];
    const int tid = threadIdx.x;
    const int bm = blockIdx.x * 64, bn = blockIdx.y * 64;
    const int tm = (tid >> 4) * 4, tn = (tid & 15) * 4;
    const int arow = tid >> 2, akq = (tid & 3) << 2;
    float acc[4][4] = {};
    for (int k0 = 0; k0 < K; k0 += 16) {
        {
            int m = bm + arow;
            float4 v = make_float4(0.f, 0.f, 0.f, 0.f);
            if (m < M) v = *(const float4*)(A + (size_t)m * K + k0 + akq);
            As[akq + 0][arow] = v.x; As[akq + 1][arow] = v.y;
            As[akq + 2][arow] = v.z; As[akq + 3][arow] = v.w;
        }
        {
            int kk = tid >> 4, nq = (tid & 15) << 2;
            float4 v = *(const float4*)(B + (size_t)(k0 + kk) * N + bn + nq);
            *(float4*)&Bs[kk][nq] = v;
        }
        __syncthreads();
#pragma unroll
        for (int kk2 = 0; kk2 < 16; ++kk2) {
            float4 a = *(const float4*)&As[kk2][tm];
            float4 b = *(const float4*)&Bs[kk2][tn];
            float av[4] = {a.x, a.y, a.z, a.w};
            float bv[4] = {b.x, b.y, b.z, b.w};
#pragma unroll
            for (int i = 0; i < 4; ++i)
#pragma unroll
                for (int jj = 0; jj < 4; ++jj)
                    acc[i][jj] = fmaf(av[i], bv[jj], acc[i][jj]);
        }
        __syncthreads();
    }
#pragma unroll
    for (int i = 0; i < 4; ++i) {
        int m = bm + tm + i;
        if (m < M)
            *(float4*)(C + (size_t)m * N + bn + tn) =
                make_float4(acc[i][0], acc[i][1], acc[i][2], acc[i][3]);
    }
}

// ---------------------------------------------------------------------------
// persistent 2-layer LSTM, data-as-flag sync.  96 blocks x 1024 threads,
// 1 block/CU (launch_bounds 1024,4 -> 128 VGPR cap, weights reg-resident).
// S0/S1: [66][8][256] u64 slots, payload = (fp32 h | tag), tag = state index+1.
// Consumers poll their own payload; producer stores are fire-and-forget.
// ---------------------------------------------------------------------------
__device__ __forceinline__ float dot16(const float4* w, const float* hp) {
    float4 s = make_float4(0.f, 0.f, 0.f, 0.f);
#pragma unroll
    for (int k = 0; k < 16; ++k) {
        float4 h4 = *(const float4*)(hp + 4 * k);
        s.x = fmaf(w[k].x, h4.x, s.x);
        s.y = fmaf(w[k].y, h4.y, s.y);
        s.z = fmaf(w[k].z, h4.z, s.z);
        s.w = fmaf(w[k].w, h4.w, s.w);
    }
    return (s.x + s.y) + (s.z + s.w);
}

__device__ __forceinline__ float poll_h(const unsigned long long* p, unsigned want) {
    unsigned long long u = __hip_atomic_load(p, __ATOMIC_RELAXED, __HIP_MEMORY_SCOPE_AGENT);
    while ((unsigned)(u >> 32) != want) {
        __builtin_amdgcn_s_sleep(1);
        u = __hip_atomic_load(p, __ATOMIC_RELAXED, __HIP_MEMORY_SCOPE_AGENT);
    }
    return __uint_as_float((unsigned)u);
}

__global__ void __launch_bounds__(1024, 4) lstm_kernel(
    const float* __restrict__ w_ih, const float* __restrict__ w_hh,
    const float* __restrict__ b_ih, const float* __restrict__ b_hh,
    const float* __restrict__ xg0, const float* __restrict__ init_c,
    unsigned long long* __restrict__ S0, unsigned long long* __restrict__ S1,
    float* __restrict__ query)
{
    __shared__ float hls[64 * 68];
    __shared__ float part[1024];
    const int tid = threadIdx.x;
    const int blk = blockIdx.x;
    // staging map (thread tid stages payload pair 2tid, 2tid+1)
    const int g = tid * 2;
    const int sb = g >> 8, r0 = g & 255, sg0 = r0 >> 6, kq = r0 & 63;
    float* const dst = &hls[(sg0 * 8 + sb) * 68 + kq];

    if (blk < 32) {
        // ------------------------ layer 0 ------------------------
        const int jl = tid & 7, gate = (tid >> 3) & 3, b = (tid >> 5) & 7, seg = tid >> 8;
        const int j0 = blk * 8, j = j0 + jl;
        float4 w[16];
        {
            const float4* wr = (const float4*)(w_hh + (size_t)(gate * HH + j) * HH + seg * 64);
#pragma unroll
            for (int k = 0; k < 16; ++k) w[k] = wr[k];
        }
        const int fj = tid >> 3, fb = tid & 7;   // finisher mapping (tid<64)
        float creg = (tid < 64) ? init_c[j0 + fj] : 0.f;
        const int chunk = seg * 8 + b;
        const int pidx = (chunk * 8 + jl) * 4 + gate;

        for (int t = 0; t < SS; ++t) {
            float xg[4];
            if (tid < 64) {
                const float* xp = xg0 + ((size_t)fb * SS + t) * G4 + (j0 + fj);
#pragma unroll
                for (int gg = 0; gg < 4; ++gg) xg[gg] = xp[gg * 256];
            }
            {   // poll+stage h0^{t} (tag t+1)
                const unsigned long long* src = S0 + (size_t)t * 2048 + g;
                dst[0] = poll_h(src, (unsigned)(t + 1));
                dst[1] = poll_h(src + 1, (unsigned)(t + 1));
            }
            __syncthreads();
            part[pidx] = dot16(w, &hls[chunk * 68]);
            __syncthreads();
            if (tid < 64) {
                float g0 = xg[0], g1 = xg[1], g2 = xg[2], g3 = xg[3];
#pragma unroll
                for (int s2 = 0; s2 < 4; ++s2) {
                    const float* pp = &part[((s2 * 8 + fb) * 8 + fj) * 4];
                    g0 += pp[0]; g1 += pp[1]; g2 += pp[2]; g3 += pp[3];
                }
                float c = fsigmoid(g1) * creg + fsigmoid(g0) * ftanh(g2);
                float h = fsigmoid(g3) * ftanh(c);
                creg = c;
                unsigned long long u = ((unsigned long long)(unsigned)(t + 2) << 32)
                                     | (unsigned long long)(unsigned)__float_as_uint(h);
                __hip_atomic_store(S0 + (size_t)(t + 1) * 2048 + fb * 256 + (j0 + fj), u,
                                   __ATOMIC_RELAXED, __HIP_MEMORY_SCOPE_AGENT);
            }
        }
    } else {
        // ------------------------ layer 1 ------------------------
        const int jl = tid & 3, gate = (tid >> 2) & 3, b = (tid >> 4) & 7, seg = tid >> 7;
        const int j0 = (blk - 32) * 4, j = j0 + jl;
        float4 w[16];
        {
            const float* base = (seg < 4)
                ? (w_ih + (size_t)(G4 + gate * HH + j) * HH + seg * 64)
                : (w_hh + (size_t)(G4 + gate * HH + j) * HH + (seg - 4) * 64);
            const float4* wr = (const float4*)base;
#pragma unroll
            for (int k = 0; k < 16; ++k) w[k] = wr[k];
        }
        const int fj = tid >> 3, fb = tid & 7;   // finisher mapping (tid<32)
        float creg = 0.f, bias[4] = {0.f, 0.f, 0.f, 0.f};
        if (tid < 32) {
            creg = init_c[HH + j0 + fj];
#pragma unroll
            for (int gg = 0; gg < 4; ++gg)
                bias[gg] = b_ih[G4 + gg * HH + j0 + fj] + b_hh[G4 + gg * HH + j0 + fj];
        }
        const int chunk = seg * 8 + b;
        const int pidx = chunk * 16 + jl * 4 + gate;

        for (int t = 0; t < SS; ++t) {
            {   // poll+stage h0^{t+1} (tag t+2) -> chunks 0..31
                const unsigned long long* src = S0 + (size_t)(t + 1) * 2048 + g;
                dst[0] = poll_h(src, (unsigned)(t + 2));
                dst[1] = poll_h(src + 1, (unsigned)(t + 2));
            }
            __syncthreads();
            if (seg < 4) part[pidx] = dot16(w, &hls[chunk * 68]);
            {   // poll+stage h1^{t} (tag t+1) -> chunks 32..63
                const unsigned long long* src = S1 + (size_t)t * 2048 + g;
                float v0 = poll_h(src, (unsigned)(t + 1));
                float v1 = poll_h(src + 1, (unsigned)(t + 1));
                dst[32 * 68 + 0] = v0;
                dst[32 * 68 + 1] = v1;
            }
            __syncthreads();
            if (seg >= 4) part[pidx] = dot16(w, &hls[chunk * 68]);  // chunk in 32..63
            __syncthreads();
            if (tid < 32) {
                float g0 = bias[0], g1 = bias[1], g2 = bias[2], g3 = bias[3];
#pragma unroll
                for (int s2 = 0; s2 < 8; ++s2) {
                    const float* pp = &part[(s2 * 8 + fb) * 16 + fj * 4];
                    g0 += pp[0]; g1 += pp[1]; g2 += pp[2]; g3 += pp[3];
                }
                float c = fsigmoid(g1) * creg + fsigmoid(g0) * ftanh(g2);
                float h = fsigmoid(g3) * ftanh(c);
                creg = c;
                int jj = j0 + fj;
                unsigned long long u = ((unsigned long long)(unsigned)(t + 2) << 32)
                                     | (unsigned long long)(unsigned)__float_as_uint(h);
                __hip_atomic_store(S1 + (size_t)(t + 1) * 2048 + fb * 256 + jj, u,
                                   __ATOMIC_RELAXED, __HIP_MEMORY_SCOPE_AGENT);
                query[((size_t)fb * SS + t) * HH + jj] = h;
            }
        }
    }
}

// ---------------------------------------------------------------------------
// additive score: out[b,s,n] = sum_h tanh(feat[b,n,h] + q[b,s,h]) * v[h]
// masked region written NEG; valid region 2-deep load-pipelined.
// ---------------------------------------------------------------------------
__global__ void score_kernel(const float* __restrict__ feat, const float* __restrict__ q,
                             const float* __restrict__ v, const int* __restrict__ mem_sizes,
                             float* __restrict__ out, int masked) {
    const int s = blockIdx.x, b = blockIdx.y;
    __shared__ float qs[256], vs[256];
    const int tid = threadIdx.x;
    qs[tid] = q[((size_t)b * SS + s) * HH + tid];
    vs[tid] = v[tid];
    __syncthreads();
    const int lane = tid & 63, wv = tid >> 6;
    const int msize = masked ? mem_sizes[b] : NN;
    const float* fb = feat + (size_t)b * NN * HH + (lane << 2);
    float* ob = out + ((size_t)b * SS + s) * NN;
    for (int n = msize + tid; n < NN; n += 256) ob[n] = -1e18f;
    float4 q4 = *(const float4*)&qs[lane << 2];
    float4 v4 = *(const float4*)&vs[lane << 2];
    int n = wv;
    for (; n + 4 < msize; n += 8) {
        float4 fa = *(const float4*)(fb + (size_t)n * HH);
        float4 fc = *(const float4*)(fb + (size_t)(n + 4) * HH);
        float a0 = ftanh(fa.x + q4.x) * v4.x + ftanh(fa.y + q4.y) * v4.y
                 + ftanh(fa.z + q4.z) * v4.z + ftanh(fa.w + q4.w) * v4.w;
        float a1 = ftanh(fc.x + q4.x) * v4.x + ftanh(fc.y + q4.y) * v4.y
                 + ftanh(fc.z + q4.z) * v4.z + ftanh(fc.w + q4.w) * v4.w;
#pragma unroll
        for (int off = 32; off; off >>= 1) {
            a0 += __shfl_xor(a0, off, 64);
            a1 += __shfl_xor(a1, off, 64);
        }
        if (lane == 0) { ob[n] = a0; ob[n + 4] = a1; }
    }
    for (; n < msize; n += 4) {
        float4 fa = *(const float4*)(fb + (size_t)n * HH);
        float a0 = ftanh(fa.x + q4.x) * v4.x + ftanh(fa.y + q4.y) * v4.y
                 + ftanh(fa.z + q4.z) * v4.z + ftanh(fa.w + q4.w) * v4.w;
#pragma unroll
        for (int off = 32; off; off >>= 1) a0 += __shfl_xor(a0, off, 64);
        if (lane == 0) ob[n] = a0;
    }
}

// ---------------------------------------------------------------------------
// fused softmax + weighted sum:  query2[b,s,h] = softmax_n(score[b,s,:]) @ feat[b,:,h]
// 5 s-rows per block; n-loop capped at mem_sizes[b] (p==0 beyond, exactly).
// ---------------------------------------------------------------------------
__global__ void swsum_kernel(const float* __restrict__ score, const float* __restrict__ feat,
                             const int* __restrict__ mem_sizes, float* __restrict__ out) {
    const int b = blockIdx.y, s0 = blockIdx.x * 5;
    const int tid = threadIdx.x;
    __shared__ float ns[5][512];
    for (int i = tid; i < 5 * 512; i += 256)
        ns[i >> 9][i & 511] = score[((size_t)b * SS + s0 + (i >> 9)) * NN + (i & 511)];
    __syncthreads();
    const int wv = tid >> 6, lane = tid & 63;
    for (int r2 = wv; r2 < 5; r2 += 4) {
        float vv[8];
#pragma unroll
        for (int k = 0; k < 8; ++k) vv[k] = ns[r2][lane + 64 * k];
        float m = vv[0];
#pragma unroll
        for (int k = 1; k < 8; ++k) m = fmaxf(m, vv[k]);
#pragma unroll
        for (int off = 32; off; off >>= 1) m = fmaxf(m, __shfl_xor(m, off, 64));
        float l = 0.f;
#pragma unroll
        for (int k = 0; k < 8; ++k) { vv[k] = __expf(vv[k] - m); l += vv[k]; }
#pragma unroll
        for (int off = 32; off; off >>= 1) l += __shfl_xor(l, off, 64);
        float inv = __builtin_amdgcn_rcpf(l);
#pragma unroll
        for (int k = 0; k < 8; ++k) ns[r2][lane + 64 * k] = vv[k] * inv;
    }
    __syncthreads();
    const int msize = mem_sizes[b];
    const int nmax = (msize + 3) & ~3;
    float a0 = 0.f, a1 = 0.f, a2 = 0.f, a3 = 0.f, a4 = 0.f;
    const float* fb = feat + (size_t)b * NN * HH + tid;
    for (int n = 0; n < nmax; n += 4) {
        float f0 = fb[(size_t)(n + 0) * HH];
        float f1 = fb[(size_t)(n + 1) * HH];
        float f2 = fb[(size_t)(n + 2) * HH];
        float f3 = fb[(size_t)(n + 3) * HH];
        a0 += ns[0][n] * f0 + ns[0][n + 1] * f1 + ns[0][n + 2] * f2 + ns[0][n + 3] * f3;
        a1 += ns[1][n] * f0 + ns[1][n + 1] * f1 + ns[1][n + 2] * f2 + ns[1][n + 3] * f3;
        a2 += ns[2][n] * f0 + ns[2][n + 1] * f1 + ns[2][n + 2] * f2 + ns[2][n + 3] * f3;
        a3 += ns[3][n] * f0 + ns[3][n + 1] * f1 + ns[3][n + 2] * f2 + ns[3][n + 3] * f3;
        a4 += ns[4][n] * f0 + ns[4][n + 1] * f1 + ns[4][n + 2] * f2 + ns[4][n + 3] * f3;
    }
    out[((size_t)b * SS + s0 + 0) * HH + tid] = a0;
    out[((size_t)b * SS + s0 + 1) * HH + tid] = a1;
    out[((size_t)b * SS + s0 + 2) * HH + tid] = a2;
    out[((size_t)b * SS + s0 + 3) * HH + tid] = a3;
    out[((size_t)b * SS + s0 + 4) * HH + tid] = a4;
}

// ---------------------------------------------------------------------------
extern "C" void kernel_launch(void* const* d_in, const int* in_sizes, int n_in,
                              void* d_out, int out_size, void* d_ws, size_t ws_size,
                              hipStream_t stream) {
    const float* attn_mem  = (const float*)d_in[0];
    const int*   mem_sizes = (const int*)d_in[1];
    const float* lstm_in   = (const float*)d_in[2];
    const float* init_h    = (const float*)d_in[3];
    const float* init_c    = (const float*)d_in[4];
    const float* init_i    = (const float*)d_in[5];
    const float* w_ih      = (const float*)d_in[6];
    const float* w_hh      = (const float*)d_in[7];
    const float* b_ih      = (const float*)d_in[8];
    const float* b_hh      = (const float*)d_in[9];
    const float* attn_wm   = (const float*)d_in[10];
    const float* attn_wq   = (const float*)d_in[11];
    const float* attn_v    = (const float*)d_in[12];
    const float* hop_wm    = (const float*)d_in[13];
    const float* hop_wq    = (const float*)d_in[14];
    const float* hop_v     = (const float*)d_in[15];
    float* out = (float*)d_out;

    float* ws        = (float*)d_ws;
    float* attn_feat = ws;                 // 1048576 floats
    float* hop_feat  = ws + 1048576;       // 1048576
    float* seq       = ws + 2097152;       // 133120
    float* xg0       = ws + 2230272;       // 532480
    float* query     = ws + 2762752;       // 133120
    // lstm-phase (dead after lstm_kernel; overlaid by post-lstm buffers)
    unsigned long long* S0 = (unsigned long long*)(ws + 2895872); // 66*2048 u64 = 270336 floats
    unsigned long long* S1 = (unsigned long long*)(ws + 3166208); // 270336 floats
    // post-lstm overlays
    float* q1        = ws + 2895872;       // 133120
    float* score     = ws + 3028992;       // 266240
    float* query2    = ws + 3295232;       // 133120
    float* q2        = ws + 3428352;       // 133120

    prep_kernel<<<1576, 256, 0, stream>>>(lstm_in, init_i, init_h, seq, S0, S1);
    mega_gemm_kernel<<<400, 256, 0, stream>>>(attn_mem, attn_wm, hop_wm, attn_feat,
                                              hop_feat, seq, w_ih, b_ih, b_hh, xg0);
    {
        void* args[] = { (void*)&w_ih, (void*)&w_hh, (void*)&b_ih, (void*)&b_hh,
                         (void*)&xg0, (void*)&init_c, (void*)&S0, (void*)&S1,
                         (void*)&query };
        hipLaunchCooperativeKernel(lstm_kernel, dim3(96), dim3(1024), args, 0u, stream);
    }
    gemm_kernel<<<dim3(9, 4), 256, 0, stream>>>(query, hop_wq, q1, 520, 256, 256);
    score_kernel<<<dim3(65, 8), 256, 0, stream>>>(hop_feat, q1, hop_v, mem_sizes, score, 1);
    swsum_kernel<<<dim3(13, 8), 256, 0, stream>>>(score, hop_feat, mem_sizes, query2);
    gemm_kernel<<<dim3(9, 4), 256, 0, stream>>>(query2, attn_wq, q2, 520, 256, 256);
    score_kernel<<<dim3(65, 8), 256, 0, stream>>>(attn_feat, q2, attn_v, mem_sizes, out, 0);
}